// Round 4
// baseline (59682.379 us; speedup 1.0000x reference)
//
#include <hip/hip_runtime.h>
#include <stdint.h>

typedef short bf16x8 __attribute__((ext_vector_type(8)));
typedef short s16x4  __attribute__((ext_vector_type(4)));
typedef float f32x4  __attribute__((ext_vector_type(4)));

__device__ __forceinline__ short f2bf(float f) {
  unsigned u = __builtin_bit_cast(unsigned, f);
  unsigned r = (u + 0x7fffu + ((u >> 16) & 1u)) >> 16;
  return (short)r;
}
__device__ __forceinline__ float bf2f(short s) {
  unsigned u = ((unsigned)(unsigned short)s) << 16;
  return __builtin_bit_cast(float, u);
}
__device__ __forceinline__ float sigf(float x) { return 1.f / (1.f + __expf(-x)); }
__device__ __forceinline__ float tanhf_(float x) {
  float e = __expf(2.f * x);
  return 1.f - 2.f / (e + 1.f);
}
__device__ __forceinline__ float wave_sum(float v) {
#pragma unroll
  for (int o = 32; o; o >>= 1) v += __shfl_xor(v, o, 64);
  return v;
}

// ---------------- weight convert f32 -> bf16 ----------------
__global__ void cvt_k(const float* __restrict__ a, short* __restrict__ o, int n) {
  int i = (blockIdx.x * 256 + threadIdx.x) * 4;
  if (i >= n) return;
  float4 v = *(const float4*)(a + i);
  s16x4 r;
  r[0] = f2bf(v.x); r[1] = f2bf(v.y); r[2] = f2bf(v.z); r[3] = f2bf(v.w);
  *(s16x4*)(o + i) = r;
}

// ---------------- embedding gather -> bf16 x ----------------
__global__ void embed_k(const int* __restrict__ toks, const float* __restrict__ emb,
                        short* __restrict__ x) {
  const int t = blockIdx.x;  // b*S + s
  const int tok = toks[t];
  const float4* src = (const float4*)(emb + (size_t)tok * 512);
  float4 a = src[threadIdx.x * 2], b = src[threadIdx.x * 2 + 1];
  bf16x8 o;
  o[0] = f2bf(a.x); o[1] = f2bf(a.y); o[2] = f2bf(a.z); o[3] = f2bf(a.w);
  o[4] = f2bf(b.x); o[5] = f2bf(b.y); o[6] = f2bf(b.z); o[7] = f2bf(b.w);
  *(bf16x8*)(x + (size_t)t * 512 + threadIdx.x * 8) = o;
}

// ---------------- rmsnorm (bf16 x) -> bf16 nx ----------------
__global__ void rms_k(const short* __restrict__ x, const float* __restrict__ w,
                      short* __restrict__ nx, int s0, int chsh, int chm) {
  const int t = blockIdx.x, b = t >> chsh, sl = t & chm;
  const short* xr = x + ((size_t)b * 1024 + s0 + sl) * 512;
  const int d0 = threadIdx.x * 8;
  bf16x8 xv = *(const bf16x8*)(xr + d0);
  float f[8];
  float ss = 0.f;
#pragma unroll
  for (int i = 0; i < 8; ++i) { f[i] = bf2f(xv[i]); ss += f[i] * f[i]; }
  ss = wave_sum(ss);
  float rs = rsqrtf(ss * (1.f / 512.f) + 1.1920929e-07f);
  float4 w0 = *(const float4*)(w + d0), w1 = *(const float4*)(w + d0 + 4);
  bf16x8 o;
  o[0] = f2bf(f[0] * rs * w0.x); o[1] = f2bf(f[1] * rs * w0.y);
  o[2] = f2bf(f[2] * rs * w0.z); o[3] = f2bf(f[3] * rs * w0.w);
  o[4] = f2bf(f[4] * rs * w1.x); o[5] = f2bf(f[5] * rs * w1.y);
  o[6] = f2bf(f[6] * rs * w1.z); o[7] = f2bf(f[7] * rs * w1.w);
  *(bf16x8*)(nx + (size_t)t * 512 + d0) = o;
}

// ---------------- GEMM C = A * B^T, A[M][K], B[N][K] bf16, 128x128 tile ----------------
// MODE 0: xg epilogue: +bias0[col]+bias1[col], store permuted [sl][w64][grp4][q4][bb16][jj16]
// MODE 1: out epilogue: store [t][512]
template <int KD, int MODE>
__global__ __launch_bounds__(256, 2) void gemm_bt_k(
    const short* __restrict__ A, const short* __restrict__ Bw, short* __restrict__ Cb,
    const float* __restrict__ bias0, const float* __restrict__ bias1, int chsh, int chm) {
  __shared__ __align__(16) short lA[128 * 64];
  __shared__ __align__(16) short lB[128 * 64];
  const int tid = threadIdx.x, lane = tid & 63, wv = tid >> 6;
  const int wm = wv >> 1, wn = wv & 1;
  const int tm = blockIdx.x, tn = blockIdx.y;
  f32x4 acc[4][4] = {};
  const short* Abase = A + (size_t)tm * 128 * KD;
  const short* Bbase = Bw + (size_t)tn * 128 * KD;
  for (int k0 = 0; k0 < KD; k0 += 64) {
    __syncthreads();
#pragma unroll
    for (int i = 0; i < 4; ++i) {
      int e = i * 2048 + tid * 8;
      int row = e >> 6, c8 = (e >> 3) & 7;
      int dsto = row * 64 + ((c8 ^ (row & 7)) << 3);
      *(bf16x8*)(lA + dsto) = *(const bf16x8*)(Abase + (size_t)row * KD + k0 + (c8 << 3));
      *(bf16x8*)(lB + dsto) = *(const bf16x8*)(Bbase + (size_t)row * KD + k0 + (c8 << 3));
    }
    __syncthreads();
#pragma unroll
    for (int kk = 0; kk < 2; ++kk) {
      bf16x8 af[4], bfr[4];
#pragma unroll
      for (int i = 0; i < 4; ++i) {
        int ra = wm * 64 + i * 16 + (lane & 15);
        int rb = wn * 64 + i * 16 + (lane & 15);
        int k8 = kk * 4 + (lane >> 4);
        af[i] = *(const bf16x8*)(lA + ra * 64 + ((k8 ^ (ra & 7)) << 3));
        bfr[i] = *(const bf16x8*)(lB + rb * 64 + ((k8 ^ (rb & 7)) << 3));
      }
#pragma unroll
      for (int i = 0; i < 4; ++i)
#pragma unroll
        for (int j = 0; j < 4; ++j)
          acc[i][j] = __builtin_amdgcn_mfma_f32_16x16x32_bf16(af[i], bfr[j], acc[i][j], 0, 0, 0);
    }
  }
#pragma unroll
  for (int i = 0; i < 4; ++i) {
    int rbase = tm * 128 + wm * 64 + i * 16 + (lane >> 4) * 4;
#pragma unroll
    for (int j = 0; j < 4; ++j) {
      int col = tn * 128 + wn * 64 + j * 16 + (lane & 15);
      float badd = 0.f;
      if constexpr (MODE == 0) badd = bias0[col] + bias1[col];
#pragma unroll
      for (int r = 0; r < 4; ++r) {
        int rowi = rbase + r;
        float v = acc[i][j][r] + badd;
        if constexpr (MODE == 0) {
          int b = rowi >> chsh, sl = rowi & chm;
          size_t off = (size_t)sl * 262144 + (size_t)((col >> 4) & 63) * 4096 +
                       (size_t)(b >> 4) * 1024 + (size_t)(col >> 10) * 256 +
                       (size_t)(b & 15) * 16 + (size_t)(col & 15);
          Cb[off] = f2bf(v);
        } else {
          Cb[(size_t)rowi * 512 + col] = f2bf(v);
        }
      }
    }
  }
}

// ---------------- persistent LSTM recurrence, 4 batch-groups interleaved ----------------
// 64 wgs; wg w owns j-slice [w*16, w*16+16) for ALL 4 batch groups.
// Wave q = gate q, W_hh rows stationary in VGPRs (same rows serve all groups).
// Phase pipeline: while computing group g, h-loads for group g+1 are in flight.
// Ordering: vmcnt retires in-order, so flag store issued after h stores (sched_barrier
// pins compiler order) is visible only after h is visible — no vmcnt(0) drain needed.
__global__ __launch_bounds__(256, 1) void lstm_rec_k(
    const short* __restrict__ xg,   // [CH][w64][grp4][q4][bb16][jj16] bf16 (biases included)
    short* __restrict__ h_all,      // [64][CH][1024] bf16
    const short* __restrict__ Whh,  // [4096][1024] bf16 (layer slice)
    short* __restrict__ h_buf,      // [2][64][1024] bf16
    float* __restrict__ c_st,       // [64][1024] f32
    unsigned* __restrict__ flags,   // [4][64]: flags[g*64+w] = steps completed (global count)
    int step_base, int CH, int chsh) {
  const int tid = threadIdx.x, lane = tid & 63, wq = tid >> 6;
  const int w = blockIdx.x, j0 = w * 16;
  __shared__ __align__(16) short hstg[2][16384];  // 2 x 32KB ping-pong (16 batch x 1024)
  __shared__ float gates[4][16][16];              // [q][bb][jj], reused each phase
  bf16x8 wf[32];
  {
    const short* wrow = Whh + (size_t)(wq * 1024 + j0 + (lane & 15)) * 1024 + (lane >> 4) * 8;
#pragma unroll
    for (int kt = 0; kt < 32; ++kt) wf[kt] = *(const bf16x8*)(wrow + kt * 32);
  }
  const int bb = tid >> 3, jj = (tid & 7) * 2;  // valid for tid<128
  float cc0[4], cc1[4];
  const short* xgl[4];
  s16x4 cur[4];
#pragma unroll
  for (int g = 0; g < 4; ++g) {
    if (tid < 128) {
      cc0[g] = c_st[(size_t)(g * 16 + bb) * 1024 + j0 + jj];
      cc1[g] = c_st[(size_t)(g * 16 + bb) * 1024 + j0 + jj + 1];
    }
    xgl[g] = xg + (size_t)(w * 4 + g) * 1024 + wq * 256 + (lane & 15) * 16 + (lane >> 4) * 4;
    cur[g] = *(const s16x4*)xgl[g];
  }
  unsigned long long hl0[8], hl1[8];  // reg-staged h for the in-flight phase

#define ISSUE_H(sN, gN)                                                                   \
  {                                                                                       \
    const short* hsrc = h_buf + (size_t)((step_base + (sN)) & 1) * 65536 +                \
                        (size_t)((gN)*16) * 1024;                                         \
    _Pragma("unroll") for (int it = 0; it < 8; ++it) {                                    \
      int si = it * 256 + tid;                                                            \
      int kt = si >> 6, sl = si & 63;                                                     \
      const short* gp = hsrc + (size_t)(sl & 15) * 1024 + kt * 32 + (sl >> 4) * 8;        \
      hl0[it] = __hip_atomic_load((const unsigned long long*)gp, __ATOMIC_RELAXED,        \
                                  __HIP_MEMORY_SCOPE_AGENT);                              \
      hl1[it] = __hip_atomic_load((const unsigned long long*)(gp + 4), __ATOMIC_RELAXED,  \
                                  __HIP_MEMORY_SCOPE_AGENT);                              \
    }                                                                                     \
  }

  {  // prologue: group 0, step 0 (flags already >= step_base from prior dispatch/memset)
    unsigned v = __hip_atomic_load(flags + lane, __ATOMIC_RELAXED, __HIP_MEMORY_SCOPE_AGENT);
    while (!__all(v >= (unsigned)step_base)) {
      __builtin_amdgcn_s_sleep(1);
      v = __hip_atomic_load(flags + lane, __ATOMIC_RELAXED, __HIP_MEMORY_SCOPE_AGENT);
    }
    ISSUE_H(0, 0);
  }

  for (int s = 0; s < CH; ++s) {
#pragma unroll
    for (int g = 0; g < 4; ++g) {
      short* buf = hstg[g & 1];
      // (a) LDS-write the staged h fragments, then make visible
#pragma unroll
      for (int it = 0; it < 8; ++it) {
        int si = it * 256 + tid;
        unsigned long long* dst = (unsigned long long*)buf + (size_t)si * 2;
        dst[0] = hl0[it]; dst[1] = hl1[it];
      }
      __syncthreads();
      // (b) MFMA: 4 chains, xg (w/ biases) as C-init; prefetch next step's xg frag
      f32x4 a0, a1 = {0.f, 0.f, 0.f, 0.f}, a2 = {0.f, 0.f, 0.f, 0.f},
            a3 = {0.f, 0.f, 0.f, 0.f};
#pragma unroll
      for (int r = 0; r < 4; ++r) a0[r] = bf2f(cur[g][r]);
      if (s + 1 < CH) cur[g] = *(const s16x4*)(xgl[g] + (size_t)(s + 1) * 262144);
#pragma unroll
      for (int kt = 0; kt < 32; kt += 4) {
        a0 = __builtin_amdgcn_mfma_f32_16x16x32_bf16(
            wf[kt], *(const bf16x8*)(buf + kt * 512 + lane * 8), a0, 0, 0, 0);
        a1 = __builtin_amdgcn_mfma_f32_16x16x32_bf16(
            wf[kt + 1], *(const bf16x8*)(buf + (kt + 1) * 512 + lane * 8), a1, 0, 0, 0);
        a2 = __builtin_amdgcn_mfma_f32_16x16x32_bf16(
            wf[kt + 2], *(const bf16x8*)(buf + (kt + 2) * 512 + lane * 8), a2, 0, 0, 0);
        a3 = __builtin_amdgcn_mfma_f32_16x16x32_bf16(
            wf[kt + 3], *(const bf16x8*)(buf + (kt + 3) * 512 + lane * 8), a3, 0, 0, 0);
      }
      f32x4 acc = (a0 + a1) + (a2 + a3);
#pragma unroll
      for (int r = 0; r < 4; ++r) gates[wq][lane & 15][(lane >> 4) * 4 + r] = acc[r];
      __syncthreads();
      // early flag probe for next phase (hidden under elementwise)
      const int gn = (g + 1) & 3;
      const int sn = (g == 3) ? s + 1 : s;
      const bool has_next = (sn < CH);
      const unsigned need_n = (unsigned)(step_base + sn);
      unsigned pv = 0;
      if (has_next)
        pv = __hip_atomic_load(flags + gn * 64 + lane, __ATOMIC_RELAXED,
                               __HIP_MEMORY_SCOPE_AGENT);
      // (d) elementwise: c,h update; h stores issued (no drain)
      if (tid < 128) {
        float i0 = gates[0][bb][jj], i1 = gates[0][bb][jj + 1];
        float f0 = gates[1][bb][jj], f1 = gates[1][bb][jj + 1];
        float g0 = gates[2][bb][jj], g1 = gates[2][bb][jj + 1];
        float o0 = gates[3][bb][jj], o1 = gates[3][bb][jj + 1];
        cc0[g] = sigf(f0) * cc0[g] + sigf(i0) * tanhf_(g0);
        cc1[g] = sigf(f1) * cc1[g] + sigf(i1) * tanhf_(g1);
        float h0 = sigf(o0) * tanhf_(cc0[g]);
        float h1 = sigf(o1) * tanhf_(cc1[g]);
        unsigned pk = (unsigned)(unsigned short)f2bf(h0) |
                      (((unsigned)(unsigned short)f2bf(h1)) << 16);
        short* hdst = h_buf + (size_t)((step_base + s + 1) & 1) * 65536;
        __hip_atomic_store((unsigned*)(hdst + (size_t)(g * 16 + bb) * 1024 + j0 + jj), pk,
                           __ATOMIC_RELAXED, __HIP_MEMORY_SCOPE_AGENT);
        *(unsigned*)(h_all + ((size_t)(((g * 16 + bb) << chsh) + s)) * 1024 + j0 + jj) = pk;
      }
      // (e,f) finish poll, issue next phase's h loads
      if (has_next) {
        while (!__all(pv >= need_n)) {
          __builtin_amdgcn_s_sleep(1);
          pv = __hip_atomic_load(flags + gn * 64 + lane, __ATOMIC_RELAXED,
                                 __HIP_MEMORY_SCOPE_AGENT);
        }
        ISSUE_H(sn, gn);
      }
      // (g) signal: issued after h stores (in-order vmcnt retirement => ordered visibility)
      __builtin_amdgcn_sched_barrier(0);
      if (tid == 0)
        __hip_atomic_store(flags + g * 64 + w, (unsigned)(step_base + s + 1),
                           __ATOMIC_RELAXED, __HIP_MEMORY_SCOPE_AGENT);
      __builtin_amdgcn_sched_barrier(0);
    }
  }
#pragma unroll
  for (int g = 0; g < 4; ++g)
    if (tid < 128) {
      c_st[(size_t)(g * 16 + bb) * 1024 + j0 + jj] = cc0[g];
      c_st[(size_t)(g * 16 + bb) * 1024 + j0 + jj + 1] = cc1[g];
    }
#undef ISSUE_H
}

// ---------------- fused LN + residual: x += LN(out + b_out + nx) (bf16 x RMW) ----------------
__global__ void ln_k(short* __restrict__ x, const short* __restrict__ outc,
                     const short* __restrict__ nxc, const float* __restrict__ bout,
                     const float* __restrict__ lnw, const float* __restrict__ lnb,
                     int s0, int chsh, int chm) {
  const int t = blockIdx.x, b = t >> chsh, sl = t & chm;
  short* xr = x + ((size_t)b * 1024 + s0 + sl) * 512;
  const int d0 = threadIdx.x * 8;
  bf16x8 ov = *(const bf16x8*)(outc + (size_t)t * 512 + d0);
  bf16x8 nv = *(const bf16x8*)(nxc + (size_t)t * 512 + d0);
  float v[8];
  float s = 0.f, ss = 0.f;
#pragma unroll
  for (int i = 0; i < 8; ++i) {
    v[i] = bf2f(ov[i]) + bout[d0 + i] + bf2f(nv[i]);
    s += v[i]; ss += v[i] * v[i];
  }
  s = wave_sum(s); ss = wave_sum(ss);
  float mu = s * (1.f / 512.f);
  float var = ss * (1.f / 512.f) - mu * mu;
  float rsd = rsqrtf(var + 1e-5f);
  bf16x8 xv = *(const bf16x8*)(xr + d0);
  bf16x8 o;
#pragma unroll
  for (int i = 0; i < 8; ++i)
    o[i] = f2bf(bf2f(xv[i]) + (v[i] - mu) * rsd * lnw[d0 + i] + lnb[d0 + i]);
  *(bf16x8*)(xr + d0) = o;
}

// ---------------- final rmsnorm(last token) + head ----------------
__global__ void head_k(const short* __restrict__ x, const float* __restrict__ fw,
                       const float* __restrict__ hW, const float* __restrict__ hb,
                       float* __restrict__ out) {
  const int b = blockIdx.x, v = threadIdx.x;  // 128 threads
  __shared__ float xr[512];
  __shared__ float red[2];
  const short* row = x + ((size_t)b * 1024 + 1023) * 512;
  s16x4 xs = *(const s16x4*)(row + v * 4);
  float x0 = bf2f(xs[0]), x1 = bf2f(xs[1]), x2 = bf2f(xs[2]), x3 = bf2f(xs[3]);
  float ss = x0 * x0 + x1 * x1 + x2 * x2 + x3 * x3;
  ss = wave_sum(ss);
  if ((v & 63) == 0) red[v >> 6] = ss;
  __syncthreads();
  float rs = rsqrtf((red[0] + red[1]) * (1.f / 512.f) + 1.1920929e-07f);
  float4 fwv = *(const float4*)(fw + v * 4);
  xr[v * 4 + 0] = x0 * rs * fwv.x;
  xr[v * 4 + 1] = x1 * rs * fwv.y;
  xr[v * 4 + 2] = x2 * rs * fwv.z;
  xr[v * 4 + 3] = x3 * rs * fwv.w;
  __syncthreads();
  float a = hb[v];
  const float* wr = hW + (size_t)v * 512;
  for (int d = 0; d < 512; d += 4) {
    float4 w4 = *(const float4*)(wr + d);
    a += xr[d] * w4.x + xr[d + 1] * w4.y + xr[d + 2] * w4.z + xr[d + 3] * w4.w;
  }
  out[(size_t)b * 128 + v] = a;
}

extern "C" void kernel_launch(void* const* d_in, const int* in_sizes, int n_in,
                              void* d_out, int out_size, void* d_ws, size_t ws_size,
                              hipStream_t stream) {
  const int* toks = (const int*)d_in[0];
  const float* emb = (const float*)d_in[1];
  const float* prew = (const float*)d_in[2];
  const float* Wih = (const float*)d_in[3];
  const float* Whh = (const float*)d_in[4];
  const float* bih = (const float*)d_in[5];
  const float* bhh = (const float*)d_in[6];
  const float* Wout = (const float*)d_in[7];
  const float* bout = (const float*)d_in[8];
  const float* lnw = (const float*)d_in[9];
  const float* lnb = (const float*)d_in[10];
  const float* fnw = (const float*)d_in[11];
  const float* hW = (const float*)d_in[12];
  const float* hb = (const float*)d_in[13];
  (void)in_sizes; (void)n_in; (void)out_size;

  // --- workspace budget: pick chunk length CH so we fit in ws_size ---
  const size_t fixed = 4096 + 262144 + 262144                 // flags, h_buf, c_st
                     + (size_t)4096 * 512 * 2                  // wihb (per-layer)
                     + (size_t)4096 * 1024 * 2                 // whhb (per-layer)
                     + (size_t)512 * 1024 * 2                  // woutb (per-layer)
                     + (size_t)64 * 1024 * 512 * 2             // x residual bf16
                     + 16 * 256;                               // alignment slack
  int chsh = 5;  // CH=32 fallback
  for (int c = 8; c >= 5; --c) {
    size_t per = ((size_t)1 << c) * 720896;  // nx + xgb + hc per chunk-step
    if (fixed + per <= ws_size) { chsh = c; break; }
  }
  const int CH = 1 << chsh, chm = CH - 1, chunks = 1024 >> chsh;

  char* w = (char*)d_ws;
  size_t off = 0;
  auto alloc = [&](size_t sz) {
    void* p = w + off;
    off = (off + sz + 255) & ~(size_t)255;
    return p;
  };
  unsigned* flags = (unsigned*)alloc(4096);
  short* h_buf = (short*)alloc(262144);                    // [2][64][1024] bf16
  float* c_st = (float*)alloc(262144);                     // [64][1024] f32
  short* wihb = (short*)alloc((size_t)4096 * 512 * 2);
  short* whhb = (short*)alloc((size_t)4096 * 1024 * 2);
  short* woutb = (short*)alloc((size_t)512 * 1024 * 2);
  short* x = (short*)alloc((size_t)64 * 1024 * 512 * 2);   // residual stream bf16
  short* nx = (short*)alloc((size_t)64 * CH * 512 * 2);    // chunk rmsnorm out
  short* hc = (short*)alloc((size_t)64 * CH * 1024 * 2);   // chunk h
  short* xgb = (short*)alloc((size_t)CH * 64 * 4096 * 2);  // chunk xg (permuted)
  short* outc = xgb;                                       // alias: xgb dead when outc written

  hipMemsetAsync(flags, 0, 4096, stream);
  embed_k<<<65536, 64, 0, stream>>>(toks, emb, x);

  for (int l = 0; l < 4; ++l) {
    hipMemsetAsync(h_buf, 0, 262144 + 262144, stream);  // zero h state + c state
    cvt_k<<<2048, 256, 0, stream>>>(Wih + (size_t)l * 4096 * 512, wihb, 4096 * 512);
    cvt_k<<<4096, 256, 0, stream>>>(Whh + (size_t)l * 4096 * 1024, whhb, 4096 * 1024);
    cvt_k<<<512, 256, 0, stream>>>(Wout + (size_t)l * 512 * 1024, woutb, 512 * 1024);
    for (int ch = 0; ch < chunks; ++ch) {
      const int s0 = ch * CH;
      rms_k<<<64 * CH, 64, 0, stream>>>(x, prew + l * 512, nx, s0, chsh, chm);
      gemm_bt_k<512, 0><<<dim3(CH / 2, 32), 256, 0, stream>>>(
          nx, wihb, xgb, bih + l * 4096, bhh + l * 4096, chsh, chm);
      lstm_rec_k<<<64, 256, 0, stream>>>(xgb, hc, whhb, h_buf, c_st, flags,
                                         l * 1024 + s0, CH, chsh);
      gemm_bt_k<1024, 1><<<dim3(CH / 2, 4), 256, 0, stream>>>(
          hc, woutb, outc, nullptr, nullptr, chsh, chm);
      ln_k<<<64 * CH, 64, 0, stream>>>(x, outc, nx, bout + l * 512, lnw + l * 512,
                                       lnb + l * 512, s0, chsh, chm);
    }
  }
  head_k<<<64, 128, 0, stream>>>(x, fnw, hW, hb, (float*)d_out);
}

// Round 5
// 24937.163 us; speedup vs baseline: 2.3933x; 2.3933x over previous
//
#include <hip/hip_runtime.h>
#include <stdint.h>

typedef short bf16x8 __attribute__((ext_vector_type(8)));
typedef short s16x4  __attribute__((ext_vector_type(4)));
typedef float f32x4  __attribute__((ext_vector_type(4)));

__device__ __forceinline__ short f2bf(float f) {
  unsigned u = __builtin_bit_cast(unsigned, f);
  unsigned r = (u + 0x7fffu + ((u >> 16) & 1u)) >> 16;
  return (short)r;
}
__device__ __forceinline__ float bf2f(short s) {
  unsigned u = ((unsigned)(unsigned short)s) << 16;
  return __builtin_bit_cast(float, u);
}
__device__ __forceinline__ float sigf(float x) { return 1.f / (1.f + __expf(-x)); }
__device__ __forceinline__ float tanhf_(float x) {
  float e = __expf(2.f * x);
  return 1.f - 2.f / (e + 1.f);
}
__device__ __forceinline__ float wave_sum(float v) {
#pragma unroll
  for (int o = 32; o; o >>= 1) v += __shfl_xor(v, o, 64);
  return v;
}

// ---------------- weight convert f32 -> bf16 ----------------
__global__ void cvt_k(const float* __restrict__ a, short* __restrict__ o, int n) {
  int i = (blockIdx.x * 256 + threadIdx.x) * 4;
  if (i >= n) return;
  float4 v = *(const float4*)(a + i);
  s16x4 r;
  r[0] = f2bf(v.x); r[1] = f2bf(v.y); r[2] = f2bf(v.z); r[3] = f2bf(v.w);
  *(s16x4*)(o + i) = r;
}

// ---------------- embedding gather -> bf16 x ----------------
__global__ void embed_k(const int* __restrict__ toks, const float* __restrict__ emb,
                        short* __restrict__ x) {
  const int t = blockIdx.x;  // b*S + s
  const int tok = toks[t];
  const float4* src = (const float4*)(emb + (size_t)tok * 512);
  float4 a = src[threadIdx.x * 2], b = src[threadIdx.x * 2 + 1];
  bf16x8 o;
  o[0] = f2bf(a.x); o[1] = f2bf(a.y); o[2] = f2bf(a.z); o[3] = f2bf(a.w);
  o[4] = f2bf(b.x); o[5] = f2bf(b.y); o[6] = f2bf(b.z); o[7] = f2bf(b.w);
  *(bf16x8*)(x + (size_t)t * 512 + threadIdx.x * 8) = o;
}

// ---------------- rmsnorm (bf16 x) -> bf16 nx ----------------
__global__ void rms_k(const short* __restrict__ x, const float* __restrict__ w,
                      short* __restrict__ nx, int s0, int chsh, int chm) {
  const int t = blockIdx.x, b = t >> chsh, sl = t & chm;
  const short* xr = x + ((size_t)b * 1024 + s0 + sl) * 512;
  const int d0 = threadIdx.x * 8;
  bf16x8 xv = *(const bf16x8*)(xr + d0);
  float f[8];
  float ss = 0.f;
#pragma unroll
  for (int i = 0; i < 8; ++i) { f[i] = bf2f(xv[i]); ss += f[i] * f[i]; }
  ss = wave_sum(ss);
  float rs = rsqrtf(ss * (1.f / 512.f) + 1.1920929e-07f);
  float4 w0 = *(const float4*)(w + d0), w1 = *(const float4*)(w + d0 + 4);
  bf16x8 o;
  o[0] = f2bf(f[0] * rs * w0.x); o[1] = f2bf(f[1] * rs * w0.y);
  o[2] = f2bf(f[2] * rs * w0.z); o[3] = f2bf(f[3] * rs * w0.w);
  o[4] = f2bf(f[4] * rs * w1.x); o[5] = f2bf(f[5] * rs * w1.y);
  o[6] = f2bf(f[6] * rs * w1.z); o[7] = f2bf(f[7] * rs * w1.w);
  *(bf16x8*)(nx + (size_t)t * 512 + d0) = o;
}

// ---------------- GEMM C = A * B^T, A[M][K], B[N][K] bf16, 128x128 tile ----------------
// MODE 0: xg epilogue: +bias0[col]+bias1[col], store permuted [sl][w64][grp4][q4][bb16][jj16]
// MODE 1: out epilogue: store [t][512]
template <int KD, int MODE>
__global__ __launch_bounds__(256, 2) void gemm_bt_k(
    const short* __restrict__ A, const short* __restrict__ Bw, short* __restrict__ Cb,
    const float* __restrict__ bias0, const float* __restrict__ bias1, int chsh, int chm) {
  __shared__ __align__(16) short lA[128 * 64];
  __shared__ __align__(16) short lB[128 * 64];
  const int tid = threadIdx.x, lane = tid & 63, wv = tid >> 6;
  const int wm = wv >> 1, wn = wv & 1;
  const int tm = blockIdx.x, tn = blockIdx.y;
  f32x4 acc[4][4] = {};
  const short* Abase = A + (size_t)tm * 128 * KD;
  const short* Bbase = Bw + (size_t)tn * 128 * KD;
  for (int k0 = 0; k0 < KD; k0 += 64) {
    __syncthreads();
#pragma unroll
    for (int i = 0; i < 4; ++i) {
      int e = i * 2048 + tid * 8;
      int row = e >> 6, c8 = (e >> 3) & 7;
      int dsto = row * 64 + ((c8 ^ (row & 7)) << 3);
      *(bf16x8*)(lA + dsto) = *(const bf16x8*)(Abase + (size_t)row * KD + k0 + (c8 << 3));
      *(bf16x8*)(lB + dsto) = *(const bf16x8*)(Bbase + (size_t)row * KD + k0 + (c8 << 3));
    }
    __syncthreads();
#pragma unroll
    for (int kk = 0; kk < 2; ++kk) {
      bf16x8 af[4], bfr[4];
#pragma unroll
      for (int i = 0; i < 4; ++i) {
        int ra = wm * 64 + i * 16 + (lane & 15);
        int rb = wn * 64 + i * 16 + (lane & 15);
        int k8 = kk * 4 + (lane >> 4);
        af[i] = *(const bf16x8*)(lA + ra * 64 + ((k8 ^ (ra & 7)) << 3));
        bfr[i] = *(const bf16x8*)(lB + rb * 64 + ((k8 ^ (rb & 7)) << 3));
      }
#pragma unroll
      for (int i = 0; i < 4; ++i)
#pragma unroll
        for (int j = 0; j < 4; ++j)
          acc[i][j] = __builtin_amdgcn_mfma_f32_16x16x32_bf16(af[i], bfr[j], acc[i][j], 0, 0, 0);
    }
  }
#pragma unroll
  for (int i = 0; i < 4; ++i) {
    int rbase = tm * 128 + wm * 64 + i * 16 + (lane >> 4) * 4;
#pragma unroll
    for (int j = 0; j < 4; ++j) {
      int col = tn * 128 + wn * 64 + j * 16 + (lane & 15);
      float badd = 0.f;
      if constexpr (MODE == 0) badd = bias0[col] + bias1[col];
#pragma unroll
      for (int r = 0; r < 4; ++r) {
        int rowi = rbase + r;
        float v = acc[i][j][r] + badd;
        if constexpr (MODE == 0) {
          int b = rowi >> chsh, sl = rowi & chm;
          size_t off = (size_t)sl * 262144 + (size_t)((col >> 4) & 63) * 4096 +
                       (size_t)(b >> 4) * 1024 + (size_t)(col >> 10) * 256 +
                       (size_t)(b & 15) * 16 + (size_t)(col & 15);
          Cb[off] = f2bf(v);
        } else {
          Cb[(size_t)rowi * 512 + col] = f2bf(v);
        }
      }
    }
  }
}

// ---------------- persistent LSTM recurrence: barrier-free data-as-signal ring --------
// 256 wgs: grp = bid>>6 (16 batches), w = bid&63 (16 j-cols). Wave q = gate q, W_hh rows
// stationary. Ring of CH+1 slots [64][1024] bf16, sentinel 0x7F7F (impossible for |h|<1).
// Writer: plain agent-scope 4B stores into slot s+1 (no drain, no signal).
// Reader: polls its 16 x 8B loads of slot s, re-issuing only sentinel words.
__global__ __launch_bounds__(256, 1) void lstm_rec_k(
    const short* __restrict__ xg,   // [CH][w64][grp4][q4][bb16][jj16] bf16 (biases included)
    short* __restrict__ h_all,      // [64][CH][1024] bf16
    const short* __restrict__ Whh,  // [4096][1024] bf16 (layer slice)
    short* __restrict__ ring,       // [CH+1][64][1024] bf16
    float* __restrict__ c_st,       // [64][1024] f32
    int CH, int chsh) {
  const int tid = threadIdx.x, lane = tid & 63, wq = tid >> 6;
  const int grp = blockIdx.x >> 6, w = blockIdx.x & 63;
  const int j0 = w * 16, b0 = grp * 16;
  __shared__ __align__(16) short hstg[16384];  // 32KB B-frag packed h (16 batch x 1024)
  __shared__ float gates[4][16][16];           // [q][bb][jj]
  bf16x8 wf[32];
  {
    const short* wrow = Whh + (size_t)(wq * 1024 + j0 + (lane & 15)) * 1024 + (lane >> 4) * 8;
#pragma unroll
    for (int kt = 0; kt < 32; ++kt) wf[kt] = *(const bf16x8*)(wrow + kt * 32);
  }
  const int bb = tid >> 3, jj = (tid & 7) * 2;  // valid for tid<128
  float c0 = 0.f, c1 = 0.f;
  if (tid < 128) {
    c0 = c_st[(size_t)(b0 + bb) * 1024 + j0 + jj];
    c1 = c_st[(size_t)(b0 + bb) * 1024 + j0 + jj + 1];
  }
  const short* xgl = xg + (size_t)(w * 4 + grp) * 1024 + wq * 256 +
                     (size_t)(lane & 15) * 16 + (lane >> 4) * 4;
  s16x4 cur = *(const s16x4*)xgl;  // step 0 xg fragment

  for (int s = 0; s < CH; ++s) {
    const short* slot = ring + (size_t)s * 65536;
    unsigned long long hl0[8], hl1[8];
    unsigned mask = 0;
    while (mask != 0xFFFFu) {
#pragma unroll
      for (int it = 0; it < 8; ++it) {
        int si = it * 256 + tid;
        int kt = si >> 6, sl = si & 63;
        const short* gp = slot + (size_t)(b0 + (sl & 15)) * 1024 + kt * 32 + (sl >> 4) * 8;
        if (!(mask & (1u << (2 * it))))
          hl0[it] = __hip_atomic_load((const unsigned long long*)gp, __ATOMIC_RELAXED,
                                      __HIP_MEMORY_SCOPE_AGENT);
        if (!(mask & (1u << (2 * it + 1))))
          hl1[it] = __hip_atomic_load((const unsigned long long*)(gp + 4), __ATOMIC_RELAXED,
                                      __HIP_MEMORY_SCOPE_AGENT);
      }
      unsigned m = 0;
#pragma unroll
      for (int it = 0; it < 8; ++it) {
        unsigned ok0 = (((unsigned)hl0[it] != 0x7F7F7F7Fu) &
                        ((unsigned)(hl0[it] >> 32) != 0x7F7F7F7Fu)) ? 1u : 0u;
        unsigned ok1 = (((unsigned)hl1[it] != 0x7F7F7F7Fu) &
                        ((unsigned)(hl1[it] >> 32) != 0x7F7F7F7Fu)) ? 1u : 0u;
        m |= (ok0 << (2 * it)) | (ok1 << (2 * it + 1));
      }
      mask = m;
      if (mask != 0xFFFFu) __builtin_amdgcn_s_sleep(1);
    }
    // LDS stage
#pragma unroll
    for (int it = 0; it < 8; ++it) {
      int si = it * 256 + tid;
      unsigned long long* dst = (unsigned long long*)hstg + (size_t)si * 2;
      dst[0] = hl0[it]; dst[1] = hl1[it];
    }
    __syncthreads();
    // MFMA: 4 independent chains; xg (incl. biases) as C-init of chain 0
    f32x4 a0, a1 = {0.f, 0.f, 0.f, 0.f}, a2 = {0.f, 0.f, 0.f, 0.f}, a3 = {0.f, 0.f, 0.f, 0.f};
#pragma unroll
    for (int r = 0; r < 4; ++r) a0[r] = bf2f(cur[r]);
    if (s + 1 < CH) cur = *(const s16x4*)(xgl + (size_t)(s + 1) * 262144);  // prefetch
#pragma unroll
    for (int kt = 0; kt < 32; kt += 4) {
      a0 = __builtin_amdgcn_mfma_f32_16x16x32_bf16(
          wf[kt], *(const bf16x8*)(hstg + kt * 512 + lane * 8), a0, 0, 0, 0);
      a1 = __builtin_amdgcn_mfma_f32_16x16x32_bf16(
          wf[kt + 1], *(const bf16x8*)(hstg + (kt + 1) * 512 + lane * 8), a1, 0, 0, 0);
      a2 = __builtin_amdgcn_mfma_f32_16x16x32_bf16(
          wf[kt + 2], *(const bf16x8*)(hstg + (kt + 2) * 512 + lane * 8), a2, 0, 0, 0);
      a3 = __builtin_amdgcn_mfma_f32_16x16x32_bf16(
          wf[kt + 3], *(const bf16x8*)(hstg + (kt + 3) * 512 + lane * 8), a3, 0, 0, 0);
    }
    f32x4 acc = (a0 + a1) + (a2 + a3);
#pragma unroll
    for (int r = 0; r < 4; ++r) gates[wq][lane & 15][(lane >> 4) * 4 + r] = acc[r];
    __syncthreads();
    if (tid < 128) {
      float i0 = gates[0][bb][jj], i1 = gates[0][bb][jj + 1];
      float f0 = gates[1][bb][jj], f1 = gates[1][bb][jj + 1];
      float g0 = gates[2][bb][jj], g1 = gates[2][bb][jj + 1];
      float o0 = gates[3][bb][jj], o1 = gates[3][bb][jj + 1];
      c0 = sigf(f0) * c0 + sigf(i0) * tanhf_(g0);
      c1 = sigf(f1) * c1 + sigf(i1) * tanhf_(g1);
      float h0 = sigf(o0) * tanhf_(c0);
      float h1 = sigf(o1) * tanhf_(c1);
      unsigned pk = (unsigned)(unsigned short)f2bf(h0) |
                    (((unsigned)(unsigned short)f2bf(h1)) << 16);
      // data IS the signal: store to next ring slot, no drain/barrier
      __hip_atomic_store(
          (unsigned*)(ring + (size_t)(s + 1) * 65536 + (size_t)(b0 + bb) * 1024 + j0 + jj),
          pk, __ATOMIC_RELAXED, __HIP_MEMORY_SCOPE_AGENT);
      *(unsigned*)(h_all + ((size_t)(((b0 + bb) << chsh) + s)) * 1024 + j0 + jj) = pk;
    }
  }
  if (tid < 128) {
    c_st[(size_t)(b0 + bb) * 1024 + j0 + jj] = c0;
    c_st[(size_t)(b0 + bb) * 1024 + j0 + jj + 1] = c1;
  }
}

// ---------------- fused LN + residual: x += LN(out + b_out + nx) (bf16 x RMW) ----------------
__global__ void ln_k(short* __restrict__ x, const short* __restrict__ outc,
                     const short* __restrict__ nxc, const float* __restrict__ bout,
                     const float* __restrict__ lnw, const float* __restrict__ lnb,
                     int s0, int chsh, int chm) {
  const int t = blockIdx.x, b = t >> chsh, sl = t & chm;
  short* xr = x + ((size_t)b * 1024 + s0 + sl) * 512;
  const int d0 = threadIdx.x * 8;
  bf16x8 ov = *(const bf16x8*)(outc + (size_t)t * 512 + d0);
  bf16x8 nv = *(const bf16x8*)(nxc + (size_t)t * 512 + d0);
  float v[8];
  float s = 0.f, ss = 0.f;
#pragma unroll
  for (int i = 0; i < 8; ++i) {
    v[i] = bf2f(ov[i]) + bout[d0 + i] + bf2f(nv[i]);
    s += v[i]; ss += v[i] * v[i];
  }
  s = wave_sum(s); ss = wave_sum(ss);
  float mu = s * (1.f / 512.f);
  float var = ss * (1.f / 512.f) - mu * mu;
  float rsd = rsqrtf(var + 1e-5f);
  bf16x8 xv = *(const bf16x8*)(xr + d0);
  bf16x8 o;
#pragma unroll
  for (int i = 0; i < 8; ++i)
    o[i] = f2bf(bf2f(xv[i]) + (v[i] - mu) * rsd * lnw[d0 + i] + lnb[d0 + i]);
  *(bf16x8*)(xr + d0) = o;
}

// ---------------- final rmsnorm(last token) + head ----------------
__global__ void head_k(const short* __restrict__ x, const float* __restrict__ fw,
                       const float* __restrict__ hW, const float* __restrict__ hb,
                       float* __restrict__ out) {
  const int b = blockIdx.x, v = threadIdx.x;  // 128 threads
  __shared__ float xr[512];
  __shared__ float red[2];
  const short* row = x + ((size_t)b * 1024 + 1023) * 512;
  s16x4 xs = *(const s16x4*)(row + v * 4);
  float x0 = bf2f(xs[0]), x1 = bf2f(xs[1]), x2 = bf2f(xs[2]), x3 = bf2f(xs[3]);
  float ss = x0 * x0 + x1 * x1 + x2 * x2 + x3 * x3;
  ss = wave_sum(ss);
  if ((v & 63) == 0) red[v >> 6] = ss;
  __syncthreads();
  float rs = rsqrtf((red[0] + red[1]) * (1.f / 512.f) + 1.1920929e-07f);
  float4 fwv = *(const float4*)(fw + v * 4);
  xr[v * 4 + 0] = x0 * rs * fwv.x;
  xr[v * 4 + 1] = x1 * rs * fwv.y;
  xr[v * 4 + 2] = x2 * rs * fwv.z;
  xr[v * 4 + 3] = x3 * rs * fwv.w;
  __syncthreads();
  float a = hb[v];
  const float* wr = hW + (size_t)v * 512;
  for (int d = 0; d < 512; d += 4) {
    float4 w4 = *(const float4*)(wr + d);
    a += xr[d] * w4.x + xr[d + 1] * w4.y + xr[d + 2] * w4.z + xr[d + 3] * w4.w;
  }
  out[(size_t)b * 128 + v] = a;
}

extern "C" void kernel_launch(void* const* d_in, const int* in_sizes, int n_in,
                              void* d_out, int out_size, void* d_ws, size_t ws_size,
                              hipStream_t stream) {
  const int* toks = (const int*)d_in[0];
  const float* emb = (const float*)d_in[1];
  const float* prew = (const float*)d_in[2];
  const float* Wih = (const float*)d_in[3];
  const float* Whh = (const float*)d_in[4];
  const float* bih = (const float*)d_in[5];
  const float* bhh = (const float*)d_in[6];
  const float* Wout = (const float*)d_in[7];
  const float* bout = (const float*)d_in[8];
  const float* lnw = (const float*)d_in[9];
  const float* lnb = (const float*)d_in[10];
  const float* fnw = (const float*)d_in[11];
  const float* hW = (const float*)d_in[12];
  const float* hb = (const float*)d_in[13];
  (void)in_sizes; (void)n_in; (void)out_size;

  // --- workspace budget: pick chunk length CH so everything fits ---
  const size_t fixed = 262144                                 // c_st
                     + (size_t)4096 * 512 * 2                  // wihb (per-layer)
                     + (size_t)4096 * 1024 * 2                 // whhb (per-layer)
                     + (size_t)512 * 1024 * 2                  // woutb (per-layer)
                     + (size_t)64 * 1024 * 512 * 2             // x residual bf16
                     + 131072                                  // ring slot 0
                     + 32 * 256;                               // alignment slack
  int chsh = 5;  // CH=32 fallback
  for (int c = 8; c >= 5; --c) {
    // per-step: nx 64*512*2 + hc 64*1024*2 + xgb 64*4096*2 + ring slot 131072
    size_t per = ((size_t)1 << c) * (65536 + 131072 + 524288 + 131072);
    if (fixed + per <= ws_size) { chsh = c; break; }
  }
  const int CH = 1 << chsh, chm = CH - 1, chunks = 1024 >> chsh;

  char* w = (char*)d_ws;
  size_t off = 0;
  auto alloc = [&](size_t sz) {
    void* p = w + off;
    off = (off + sz + 255) & ~(size_t)255;
    return p;
  };
  float* c_st = (float*)alloc(262144);                        // [64][1024] f32
  short* ring = (short*)alloc((size_t)(CH + 1) * 131072);     // [CH+1][64][1024] bf16
  short* wihb = (short*)alloc((size_t)4096 * 512 * 2);
  short* whhb = (short*)alloc((size_t)4096 * 1024 * 2);
  short* woutb = (short*)alloc((size_t)512 * 1024 * 2);
  short* x = (short*)alloc((size_t)64 * 1024 * 512 * 2);      // residual stream bf16
  short* nx = (short*)alloc((size_t)64 * CH * 512 * 2);       // chunk rmsnorm out
  short* hc = (short*)alloc((size_t)64 * CH * 1024 * 2);      // chunk h
  short* xgb = (short*)alloc((size_t)CH * 64 * 4096 * 2);     // chunk xg (permuted)
  short* outc = xgb;                                          // alias: xgb dead when outc written

  embed_k<<<65536, 64, 0, stream>>>(toks, emb, x);

  for (int l = 0; l < 4; ++l) {
    // layer init: h_0 = 0 (slot 0), c = 0, sentinel slots 1..CH
    hipMemsetAsync(ring, 0, 131072, stream);
    hipMemsetAsync((char*)ring + 131072, 0x7F, (size_t)CH * 131072, stream);
    hipMemsetAsync(c_st, 0, 262144, stream);
    cvt_k<<<2048, 256, 0, stream>>>(Wih + (size_t)l * 4096 * 512, wihb, 4096 * 512);
    cvt_k<<<4096, 256, 0, stream>>>(Whh + (size_t)l * 4096 * 1024, whhb, 4096 * 1024);
    cvt_k<<<512, 256, 0, stream>>>(Wout + (size_t)l * 512 * 1024, woutb, 512 * 1024);
    for (int ch = 0; ch < chunks; ++ch) {
      const int s0 = ch * CH;
      rms_k<<<64 * CH, 64, 0, stream>>>(x, prew + l * 512, nx, s0, chsh, chm);
      gemm_bt_k<512, 0><<<dim3(CH / 2, 32), 256, 0, stream>>>(
          nx, wihb, xgb, bih + l * 4096, bhh + l * 4096, chsh, chm);
      lstm_rec_k<<<256, 256, 0, stream>>>(xgb, hc, whhb, ring, c_st, CH, chsh);
      if (ch + 1 < chunks) {  // next chunk's h_0 = this chunk's final h (slot CH)
        hipMemcpyAsync(ring, (char*)ring + (size_t)CH * 131072, 131072,
                       hipMemcpyDeviceToDevice, stream);
        hipMemsetAsync((char*)ring + 131072, 0x7F, (size_t)CH * 131072, stream);
      }
      gemm_bt_k<1024, 1><<<dim3(CH / 2, 4), 256, 0, stream>>>(
          hc, woutb, outc, nullptr, nullptr, chsh, chm);
      ln_k<<<64 * CH, 64, 0, stream>>>(x, outc, nx, bout + l * 512, lnw + l * 512,
                                       lnb + l * 512, s0, chsh, chm);
    }
  }
  head_k<<<64, 128, 0, stream>>>(x, fnw, hW, hb, (float*)d_out);
}